// Round 1
// baseline (532.532 us; speedup 1.0000x reference)
//
#include <hip/hip_runtime.h>
#include <hip/hip_bf16.h>

#define NUM_USERS 100000
#define NUM_ITEMS 50000
#define EMBED_DIM 64
#define N_NODES   150000                 // NUM_USERS + NUM_ITEMS
#define ROW_SHIFT 9                      // 512 rows per bucket
#define ROWS_PER_BUCKET 512
#define B_BUCKETS ((N_NODES + ROWS_PER_BUCKET - 1) / ROWS_PER_BUCKET)   // 293
#define NBP 512                          // padded bucket-array size
#define BIN_CHUNK 2048                   // edges per bin block (4/thread @512)
#define COL_MASK 0x3FFFF                 // 18 bits for col (N_NODES < 262144)

typedef unsigned short ushort_t;
typedef unsigned int uint_t;

__device__ __forceinline__ float bf16_to_f32(ushort_t u) {
    return __uint_as_float(((unsigned)u) << 16);
}
__device__ __forceinline__ ushort_t f32_to_bf16(float f) {
    return __builtin_bit_cast(ushort_t, __float2bfloat16(f));   // RNE
}
__device__ __forceinline__ float bflo(uint_t r) {               // dim 2hl
    return __uint_as_float(r << 16);
}
__device__ __forceinline__ float bfhi(uint_t r) {               // dim 2hl+1
    return __uint_as_float(r & 0xffff0000u);
}

// ---------------------------------------------------------------------------
// k_bin2: heterogeneous grid. First g_conv blocks: fp32->bf16 ego convert.
// Remaining blocks: LDS-binned staging into FIXED-CAPACITY bucket regions
// (cap entries per bucket; cursor[b] counts fill). No histogram, no global
// scan needed — bucket b's region starts at b*cap.
// Staging entry: int2 {col | lrow<<18, val}.
// ---------------------------------------------------------------------------
__global__ void __launch_bounds__(512) k_bin2(const float* __restrict__ ue,
                                              const float* __restrict__ ie,
                                              ushort_t* __restrict__ xb,
                                              const int* __restrict__ rows,
                                              const int* __restrict__ cols,
                                              const float* __restrict__ vals,
                                              int* __restrict__ cursor,
                                              int2* __restrict__ staging,
                                              int nnz, int cap, int g_conv) {
    int t = threadIdx.x;
    if ((int)blockIdx.x < g_conv) {
        // ---- convert: fp32 ego table -> bf16 (float4 granularity) ----
        int i = blockIdx.x * 512 + t;
        const int n4 = (N_NODES * EMBED_DIM) / 4;
        if (i >= n4) return;
        const int usplit = (NUM_USERS * EMBED_DIM) / 4;
        float4 f = (i < usplit) ? ((const float4*)ue)[i] : ((const float4*)ie)[i - usplit];
        ushort4 o;
        o.x = f32_to_bf16(f.x);
        o.y = f32_to_bf16(f.y);
        o.z = f32_to_bf16(f.z);
        o.w = f32_to_bf16(f.w);
        ((ushort4*)xb)[i] = o;
        return;
    }

    // ---- binning ----
    __shared__ int  ccnt[NBP];
    __shared__ int  cpos[NBP];
    __shared__ int  gdst[NBP];
    __shared__ int2 entries[BIN_CHUNK];            // 16 KB
    __shared__ ushort_t ebuck[BIN_CHUNK];          // 4 KB

    int base = (blockIdx.x - g_conv) * BIN_CHUNK;
    ccnt[t] = 0;
    __syncthreads();

    int myrow[BIN_CHUNK / 512];
#pragma unroll
    for (int k = 0; k < BIN_CHUNK / 512; k++) {
        int idx = base + k * 512 + t;
        int r = (idx < nnz) ? rows[idx] : -1;
        myrow[k] = r;
        if (r >= 0) atomicAdd(&ccnt[r >> ROW_SHIFT], 1);
    }
    __syncthreads();

    int c = ccnt[t];
    cpos[t] = c;
    __syncthreads();
    for (int d = 1; d < NBP; d <<= 1) {
        int y = (t >= d) ? cpos[t - d] : 0;
        __syncthreads();
        cpos[t] += y;
        __syncthreads();
    }
    int total = cpos[NBP - 1];
    int excl = cpos[t] - c;
    __syncthreads();
    cpos[t] = excl;
    __syncthreads();

#pragma unroll
    for (int k = 0; k < BIN_CHUNK / 512; k++) {
        int r = myrow[k];
        if (r >= 0) {
            int idx = base + k * 512 + t;
            int b = r >> ROW_SHIFT;
            int lrow = r & (ROWS_PER_BUCKET - 1);
            int slot = atomicAdd(&cpos[b], 1);
            entries[slot] = make_int2(cols[idx] | (lrow << 18), __float_as_int(vals[idx]));
            ebuck[slot] = (ushort_t)b;
        }
    }
    __syncthreads();

    // reserve space in each touched bucket's fixed region
    if (t < B_BUCKETS && ccnt[t] > 0) {
        int g = atomicAdd(&cursor[t], ccnt[t]);
        gdst[t] = t * cap + g - (cpos[t] - ccnt[t]);   // minus local run base
    }
    __syncthreads();

    for (int i = t; i < total; i += 512) {
        int eb = ebuck[i];
        int pos = gdst[eb] + i;
        if (pos < (eb + 1) * cap)                     // capacity guard (never hits)
            staging[pos] = entries[i];
    }
}

// ---------------------------------------------------------------------------
// k_scatter2b: one block owns one bucket (512 rows, fixed region).
// Count -> scan -> scatter; writes per-row ranges {beg,end} into padded cv.
// ---------------------------------------------------------------------------
__global__ void __launch_bounds__(512) k_scatter2b(const int2* __restrict__ staging,
                                                   const int* __restrict__ cursor,
                                                   int2* __restrict__ ranges,
                                                   int2* __restrict__ cv, int cap) {
    __shared__ int rc[ROWS_PER_BUCKET];
    int b = blockIdx.x;
    int t = threadIdx.x;
    int rbase = b * cap;
    int cnt_b = cursor[b];
    if (cnt_b > cap) cnt_b = cap;
    int row0 = b << ROW_SHIFT;

    rc[t] = 0;
    __syncthreads();
    for (int i = t; i < cnt_b; i += 512)
        atomicAdd(&rc[staging[rbase + i].x >> 18], 1);
    __syncthreads();

    int c = rc[t];
    for (int d = 1; d < ROWS_PER_BUCKET; d <<= 1) {
        int y = (t >= d) ? rc[t - d] : 0;
        __syncthreads();
        rc[t] += y;
        __syncthreads();
    }
    int excl = rc[t] - c;
    int row = row0 + t;
    if (row < N_NODES) ranges[row] = make_int2(rbase + excl, rbase + excl + c);
    __syncthreads();
    rc[t] = excl;                        // becomes per-row cursor
    __syncthreads();

    for (int i = t; i < cnt_b; i += 512) {
        int2 e = staging[rbase + i];
        int pos = rbase + atomicAdd(&rc[e.x >> 18], 1);
        cv[pos] = make_int2(e.x & COL_MASK, e.y);
    }
}

// ---------------------------------------------------------------------------
// Paired SpMM row body (R13). Each half-wave owns a CONTIGUOUS sub-range of
// the row's edge list: lanes 0-31 walk [beg, beg+n_lo), lanes 32-63 walk
// [beg+n_lo, end). Each lane's cv load directly yields its col/val in VGPRs
// (no readfirstlane, no even/odd cndmask selects). Still 2 rows (256B) of
// gather in flight per load instruction. Groups of 8 edges/half, 2x-unrolled
// ping-pong; leftover handled by ONE fully-unrolled masked 8-wide tail
// (replaces the serial per-pair chain; padded staging makes OOB reads safe).
// ---------------------------------------------------------------------------
#define SPMM_LOAD(R, C)                                                       \
    _Pragma("unroll")                                                         \
    for (int j = 0; j < 8; j++) C[j] = cvp[j];                                \
    _Pragma("unroll")                                                         \
    for (int j = 0; j < 8; j++) R[j] = xw[(size_t)(uint_t)C[j].x * 32 + hl];  \
    cvp += 8;

#define SPMM_CONSUME(R, C)                                                    \
    _Pragma("unroll")                                                         \
    for (int j = 0; j < 8; j++) {                                             \
        float v = __int_as_float(C[j].y);                                     \
        ax += v * bflo(R[j]);                                                 \
        ay += v * bfhi(R[j]);                                                 \
    }

__device__ __forceinline__ float2 spmm_row(int beg, int end, int hl, bool hi_half,
                                           const int2* __restrict__ cv,
                                           const ushort_t* __restrict__ xb) {
    const uint_t* __restrict__ xw = (const uint_t*)xb;
    float ax = 0.f, ay = 0.f;

    int ne   = end - beg;                // >= 0
    int n_hi = ne >> 1;                  // hi half count (floor)
    int n_lo = ne - n_hi;                // lo half count (ceil, takes odd edge)
    int my_n = hi_half ? n_hi : n_lo;    // per-lane edge count
    const int2* cvp = cv + beg + (hi_half ? n_lo : 0);   // per-lane stream ptr

    int ng = n_hi >> 3;                  // full groups of 8 edges per half

    if (ng > 0) {
        int2   c0[8], c1[8];
        uint_t r0[8], r1[8];
        SPMM_LOAD(r0, c0)                // prologue: group 0
        int g = 1;
#pragma unroll 1
        for (; g + 1 < ng; g += 2) {
            SPMM_LOAD(r1, c1)
            SPMM_CONSUME(r0, c0)
            SPMM_LOAD(r0, c0)
            SPMM_CONSUME(r1, c1)
        }
        if (g < ng) {
            SPMM_LOAD(r1, c1)
            SPMM_CONSUME(r0, c0)
            SPMM_CONSUME(r1, c1)
        } else {
            SPMM_CONSUME(r0, c0)
        }
    }

    // masked 8-wide tail: handles leftover (incl. the odd edge on the lo half).
    // rem: lo in [0,8], hi in [0,7]. Reads past a row's range stay inside the
    // padded cv allocation; invalid lanes use col=0 (hot cached line), val=0.
    int done = ng << 3;
    int rem  = my_n - done;
    if (n_lo > done) {                   // wave-uniform condition
#pragma unroll
        for (int j = 0; j < 8; j++) {
            int2 c = cvp[j];
            bool valid = j < rem;
            int col  = valid ? c.x : 0;
            float v  = valid ? __int_as_float(c.y) : 0.f;
            uint_t r = xw[(size_t)(uint_t)col * 32 + hl];
            ax += v * bflo(r);
            ay += v * bfhi(r);
        }
    }

    // combine halves: both halves end up with the full row sum
    ax += __shfl_xor(ax, 32, 64);
    ay += __shfl_xor(ay, 32, 64);
    return make_float2(ax, ay);
}

__global__ void k_spmm(const int2* __restrict__ ranges, const int2* __restrict__ cv,
                       const ushort_t* __restrict__ xb, ushort_t* __restrict__ out) {
    int row = (blockIdx.x * blockDim.x + threadIdx.x) >> 6;
    int lane = threadIdx.x & 63;
    if (row >= N_NODES) return;
    int hl = lane & 31;
    bool hi_half = lane >= 32;
    row = __builtin_amdgcn_readfirstlane(row);
    int2 rng = ranges[row];
    int beg = __builtin_amdgcn_readfirstlane(rng.x);
    int end = __builtin_amdgcn_readfirstlane(rng.y);
    float2 a = spmm_row(beg, end, hl, hi_half, cv, xb);
    if (!hi_half) {
        uint_t packed = ((uint_t)f32_to_bf16(a.y) << 16) | (uint_t)f32_to_bf16(a.x);
        ((uint_t*)out)[(size_t)row * 32 + hl] = packed;   // dims 2hl, 2hl+1
    }
}

// ---------------------------------------------------------------------------
// k_last: one wave per batch element. Computes layer-3 rows for BOTH the
// user node and item node (two spmm_rows), gathers ego(fp32)+xbA+xbB, and
// emits the dot. Halves are duplicated across lanes 0-31/32-63, so the
// 64-lane reduction double-counts: fold the /2 into the final scale (1/32).
// ---------------------------------------------------------------------------
__global__ void k_last(const int2* __restrict__ ranges, const int2* __restrict__ cv,
                       const int* __restrict__ users, const int* __restrict__ items,
                       const float* __restrict__ ue, const float* __restrict__ ie,
                       const ushort_t* __restrict__ xbA, const ushort_t* __restrict__ xbB,
                       float* __restrict__ out, int batch) {
    int w = (blockIdx.x * blockDim.x + threadIdx.x) >> 6;
    int lane = threadIdx.x & 63;
    if (w >= batch) return;
    int hl = lane & 31;
    bool hi_half = lane >= 32;

    int uu = __builtin_amdgcn_readfirstlane(users[w]);
    int ii = __builtin_amdgcn_readfirstlane(items[w]);
    int row_u = uu;
    int row_i = NUM_USERS + ii;

    // layer-3 contributions (source = xbB)
    int2 ru = ranges[row_u];
    float2 a_u = spmm_row(__builtin_amdgcn_readfirstlane(ru.x),
                          __builtin_amdgcn_readfirstlane(ru.y), hl, hi_half, cv, xbB);
    int2 ri = ranges[row_i];
    float2 a_i = spmm_row(__builtin_amdgcn_readfirstlane(ri.x),
                          __builtin_amdgcn_readfirstlane(ri.y), hl, hi_half, cv, xbB);

    // gathers at dims (2hl, 2hl+1); both halves read the same (broadcast)
    float2 e_u = ((const float2*)(ue + (size_t)uu * EMBED_DIM))[hl];
    float2 e_i = ((const float2*)(ie + (size_t)ii * EMBED_DIM))[hl];
    uint_t Au = ((const uint_t*)xbA)[(size_t)row_u * 32 + hl];
    uint_t Bu = ((const uint_t*)xbB)[(size_t)row_u * 32 + hl];
    uint_t Ai = ((const uint_t*)xbA)[(size_t)row_i * 32 + hl];
    uint_t Bi = ((const uint_t*)xbB)[(size_t)row_i * 32 + hl];

    float ux = e_u.x + bflo(Au) + bflo(Bu) + a_u.x;
    float uy = e_u.y + bfhi(Au) + bfhi(Bu) + a_u.y;
    float ix = e_i.x + bflo(Ai) + bflo(Bi) + a_i.x;
    float iy = e_i.y + bfhi(Ai) + bfhi(Bi) + a_i.y;

    float p = ux * ix + uy * iy;
#pragma unroll
    for (int d = 32; d > 0; d >>= 1) p += __shfl_down(p, d, 64);
    if (lane == 0) out[w] = p * (1.0f / 32.0f);   // 1/16 mean² scale, /2 dup halves
}

// ---------------------------------------------------------------------------

extern "C" void kernel_launch(void* const* d_in, const int* in_sizes, int n_in,
                              void* d_out, int out_size, void* d_ws, size_t ws_size,
                              hipStream_t stream) {
    const int*   users    = (const int*)  d_in[0];
    const int*   items    = (const int*)  d_in[1];
    const int*   adj_rows = (const int*)  d_in[2];
    const int*   adj_cols = (const int*)  d_in[3];
    const float* adj_vals = (const float*)d_in[4];
    const float* user_emb = (const float*)d_in[5];
    const float* item_emb = (const float*)d_in[6];
    float* out = (float*)d_out;

    const int batch = in_sizes[0];
    const int nnz   = in_sizes[2];

    // fixed bucket capacity: mean * 9/8, rounded up to 64 (16-sigma margin)
    int cap = ((nnz / B_BUCKETS) * 9 + 7) / 8;
    cap = (cap + 63) & ~63;
    const size_t padded = (size_t)B_BUCKETS * cap;   // ~5.4M entries

    char* p = (char*)d_ws;
    auto alloc = [&](size_t bytes) -> char* {
        char* r = p;
        p += (bytes + 255) & ~(size_t)255;
        return r;
    };
    const size_t xb_bytes = (size_t)N_NODES * EMBED_DIM * 2;       // 19.2 MB
    int2*     ranges = (int2*) alloc((size_t)N_NODES * 8);
    int*      cursor = (int*)  alloc(NBP * 4);
    int2*     cv     = (int2*) alloc(padded * 8);                  // padded CSR
    // region overlays: staging (build) vs xbA+xbB (layer buffers)
    size_t    region_bytes = padded * 8;
    if (region_bytes < 2 * xb_bytes) region_bytes = 2 * xb_bytes;
    char*     region  = alloc(region_bytes);
    int2*     staging = (int2*)region;
    ushort_t* xbA     = (ushort_t*)region;
    ushort_t* xbB     = (ushort_t*)(region + xb_bytes);
    ushort_t* xb_ego  = (ushort_t*)alloc(xb_bytes);

    const int g_conv  = ((N_NODES * EMBED_DIM / 4) + 511) / 512;   // 4688
    const int g_bin   = (nnz + BIN_CHUNK - 1) / BIN_CHUNK;         // 2344
    const int g_nodes = (N_NODES + 3) / 4;                         // 4 waves/block
    const int g_batch = (batch + 3) / 4;

    // ---- build: convert + fixed-capacity binning (one grid), then scatter ----
    hipMemsetAsync(cursor, 0, NBP * 4, stream);
    k_bin2<<<g_conv + g_bin, 512, 0, stream>>>(user_emb, item_emb, xb_ego,
                                               adj_rows, adj_cols, adj_vals,
                                               cursor, staging, nnz, cap, g_conv);
    k_scatter2b<<<B_BUCKETS, 512, 0, stream>>>(staging, cursor, ranges, cv, cap);

    // ---- layer 1: xbA = A * ego ----
    k_spmm<<<g_nodes, 256, 0, stream>>>(ranges, cv, xb_ego, xbA);

    // ---- layer 2: xbB = A * xbA ----
    k_spmm<<<g_nodes, 256, 0, stream>>>(ranges, cv, xbA, xbB);

    // ---- layer 3 (batch rows only) + gather + dot, fused ----
    k_last<<<g_batch, 256, 0, stream>>>(ranges, cv, users, items,
                                        user_emb, item_emb, xbA, xbB, out, batch);
}

// Round 2
// 434.914 us; speedup vs baseline: 1.2245x; 1.2245x over previous
//
#include <hip/hip_runtime.h>
#include <hip/hip_bf16.h>

#define NUM_USERS 100000
#define NUM_ITEMS 50000
#define EMBED_DIM 64
#define N_NODES   150000                 // NUM_USERS + NUM_ITEMS
#define ROW_SHIFT 9                      // 512 rows per bucket
#define ROWS_PER_BUCKET 512
#define B_BUCKETS ((N_NODES + ROWS_PER_BUCKET - 1) / ROWS_PER_BUCKET)   // 293
#define NBP 512                          // padded bucket-array size
#define BIN_CHUNK 2048                   // edges per bin block (4/thread @512)
#define COL_MASK 0x3FFFF                 // 18 bits for col (N_NODES < 262144)

typedef unsigned short ushort_t;
typedef unsigned int uint_t;

__device__ __forceinline__ float bf16_to_f32(ushort_t u) {
    return __uint_as_float(((unsigned)u) << 16);
}
__device__ __forceinline__ ushort_t f32_to_bf16(float f) {
    return __builtin_bit_cast(ushort_t, __float2bfloat16(f));   // RNE
}
__device__ __forceinline__ float bflo(uint_t r) {               // dim 2hl
    return __uint_as_float(r << 16);
}
__device__ __forceinline__ float bfhi(uint_t r) {               // dim 2hl+1
    return __uint_as_float(r & 0xffff0000u);
}

// ---------------------------------------------------------------------------
// k_bin2: heterogeneous grid. First g_conv blocks: fp32->bf16 ego convert.
// Remaining blocks: LDS-binned staging into FIXED-CAPACITY bucket regions
// (cap entries per bucket; cursor[b] counts fill). No histogram, no global
// scan needed — bucket b's region starts at b*cap.
// Staging entry: int2 {col | lrow<<18, val}.
// ---------------------------------------------------------------------------
__global__ void __launch_bounds__(512) k_bin2(const float* __restrict__ ue,
                                              const float* __restrict__ ie,
                                              ushort_t* __restrict__ xb,
                                              const int* __restrict__ rows,
                                              const int* __restrict__ cols,
                                              const float* __restrict__ vals,
                                              int* __restrict__ cursor,
                                              int2* __restrict__ staging,
                                              int nnz, int cap, int g_conv) {
    int t = threadIdx.x;
    if ((int)blockIdx.x < g_conv) {
        // ---- convert: fp32 ego table -> bf16 (float4 granularity) ----
        int i = blockIdx.x * 512 + t;
        const int n4 = (N_NODES * EMBED_DIM) / 4;
        if (i >= n4) return;
        const int usplit = (NUM_USERS * EMBED_DIM) / 4;
        float4 f = (i < usplit) ? ((const float4*)ue)[i] : ((const float4*)ie)[i - usplit];
        ushort4 o;
        o.x = f32_to_bf16(f.x);
        o.y = f32_to_bf16(f.y);
        o.z = f32_to_bf16(f.z);
        o.w = f32_to_bf16(f.w);
        ((ushort4*)xb)[i] = o;
        return;
    }

    // ---- binning ----
    __shared__ int  ccnt[NBP];
    __shared__ int  cpos[NBP];
    __shared__ int  gdst[NBP];
    __shared__ int2 entries[BIN_CHUNK];            // 16 KB
    __shared__ ushort_t ebuck[BIN_CHUNK];          // 4 KB

    int base = (blockIdx.x - g_conv) * BIN_CHUNK;
    ccnt[t] = 0;
    __syncthreads();

    int myrow[BIN_CHUNK / 512];
#pragma unroll
    for (int k = 0; k < BIN_CHUNK / 512; k++) {
        int idx = base + k * 512 + t;
        int r = (idx < nnz) ? rows[idx] : -1;
        myrow[k] = r;
        if (r >= 0) atomicAdd(&ccnt[r >> ROW_SHIFT], 1);
    }
    __syncthreads();

    int c = ccnt[t];
    cpos[t] = c;
    __syncthreads();
    for (int d = 1; d < NBP; d <<= 1) {
        int y = (t >= d) ? cpos[t - d] : 0;
        __syncthreads();
        cpos[t] += y;
        __syncthreads();
    }
    int total = cpos[NBP - 1];
    int excl = cpos[t] - c;
    __syncthreads();
    cpos[t] = excl;
    __syncthreads();

#pragma unroll
    for (int k = 0; k < BIN_CHUNK / 512; k++) {
        int r = myrow[k];
        if (r >= 0) {
            int idx = base + k * 512 + t;
            int b = r >> ROW_SHIFT;
            int lrow = r & (ROWS_PER_BUCKET - 1);
            int slot = atomicAdd(&cpos[b], 1);
            entries[slot] = make_int2(cols[idx] | (lrow << 18), __float_as_int(vals[idx]));
            ebuck[slot] = (ushort_t)b;
        }
    }
    __syncthreads();

    // reserve space in each touched bucket's fixed region
    if (t < B_BUCKETS && ccnt[t] > 0) {
        int g = atomicAdd(&cursor[t], ccnt[t]);
        gdst[t] = t * cap + g - (cpos[t] - ccnt[t]);   // minus local run base
    }
    __syncthreads();

    for (int i = t; i < total; i += 512) {
        int eb = ebuck[i];
        int pos = gdst[eb] + i;
        if (pos < (eb + 1) * cap)                     // capacity guard (never hits)
            staging[pos] = entries[i];
    }
}

// ---------------------------------------------------------------------------
// k_scatter2b: one block owns one bucket (512 rows, fixed region).
// Count -> scan -> scatter; writes per-row ranges {beg,end} into padded cv.
// ---------------------------------------------------------------------------
__global__ void __launch_bounds__(512) k_scatter2b(const int2* __restrict__ staging,
                                                   const int* __restrict__ cursor,
                                                   int2* __restrict__ ranges,
                                                   int2* __restrict__ cv, int cap) {
    __shared__ int rc[ROWS_PER_BUCKET];
    int b = blockIdx.x;
    int t = threadIdx.x;
    int rbase = b * cap;
    int cnt_b = cursor[b];
    if (cnt_b > cap) cnt_b = cap;
    int row0 = b << ROW_SHIFT;

    rc[t] = 0;
    __syncthreads();
    for (int i = t; i < cnt_b; i += 512)
        atomicAdd(&rc[staging[rbase + i].x >> 18], 1);
    __syncthreads();

    int c = rc[t];
    for (int d = 1; d < ROWS_PER_BUCKET; d <<= 1) {
        int y = (t >= d) ? rc[t - d] : 0;
        __syncthreads();
        rc[t] += y;
        __syncthreads();
    }
    int excl = rc[t] - c;
    int row = row0 + t;
    if (row < N_NODES) ranges[row] = make_int2(rbase + excl, rbase + excl + c);
    __syncthreads();
    rc[t] = excl;                        // becomes per-row cursor
    __syncthreads();

    for (int i = t; i < cnt_b; i += 512) {
        int2 e = staging[rbase + i];
        int pos = rbase + atomicAdd(&rc[e.x >> 18], 1);
        cv[pos] = make_int2(e.x & COL_MASK, e.y);
    }
}

// ---------------------------------------------------------------------------
// Paired SpMM row body (R14 = R12 main loop, known-good wave-uniform/SGPR
// edge stream + masked parallel tail). Lanes 0-31 gather edge e's row as
// ushort2 (full 128B row), lanes 32-63 edge e+1's row: 4 lines in flight per
// instruction. Edge stream wave-uniform (readfirstlane -> SGPRs). 2x-unrolled
// ping-pong, macro bodies, scalar ax/ay accumulators.
// Tail: the old serial per-pair loop (~600 cy dependent chain per pair,
// ~3.5 pairs avg) is replaced by ONE masked 8-pair burst shaped like a main
// loop group: 16 cv loads issue together, 8 gathers issue together. Validity
// masks are wave-uniform (s_cselect); invalid edges clamp col->0 (hot line,
// v=0 contribution). Reads past `end` stay inside the bucket's padded cap
// region (>=2000-entry slack), and cols are clamped BEFORE the gather so
// unwritten-slack garbage can't form wild addresses.
// ---------------------------------------------------------------------------
#define SPMM_LOAD(R, VE, VO)                                                  \
    _Pragma("unroll")                                                         \
    for (int j = 0; j < 8; j++) {                                             \
        int2 c0 = cv[e + 2 * j];                                              \
        int2 c1 = cv[e + 2 * j + 1];                                          \
        int ce = __builtin_amdgcn_readfirstlane(c0.x);                        \
        int co = __builtin_amdgcn_readfirstlane(c1.x);                        \
        VE[j] = __int_as_float(__builtin_amdgcn_readfirstlane(c0.y));         \
        VO[j] = __int_as_float(__builtin_amdgcn_readfirstlane(c1.y));         \
        int col = hi_half ? co : ce;                                          \
        R[j] = xw[(size_t)col * 32 + hl];                                     \
    }                                                                         \
    e += 16;

#define SPMM_CONSUME(R, VE, VO)                                               \
    _Pragma("unroll")                                                         \
    for (int j = 0; j < 8; j++) {                                             \
        float v = hi_half ? VO[j] : VE[j];                                    \
        ax += v * bflo(R[j]);                                                 \
        ay += v * bfhi(R[j]);                                                 \
    }

__device__ __forceinline__ float2 spmm_row(int beg, int end, int hl, bool hi_half,
                                           const int2* __restrict__ cv,
                                           const ushort_t* __restrict__ xb) {
    const uint_t* __restrict__ xw = (const uint_t*)xb;
    float ax = 0.f, ay = 0.f;
    int e = beg;
    int npair = (end - beg) >> 1;
    int ng = npair >> 3;                 // groups of 8 pairs = 16 edges

    if (ng > 0) {
        uint_t r0[8], r1[8];
        float ve0[8], vo0[8], ve1[8], vo1[8];    // wave-uniform -> SGPRs
        SPMM_LOAD(r0, ve0, vo0)                  // prologue: group 0
        int g = 1;
#pragma unroll 1
        for (; g + 1 < ng; g += 2) {
            SPMM_LOAD(r1, ve1, vo1)
            SPMM_CONSUME(r0, ve0, vo0)
            SPMM_LOAD(r0, ve0, vo0)
            SPMM_CONSUME(r1, ve1, vo1)
        }
        if (g < ng) {
            SPMM_LOAD(r1, ve1, vo1)
            SPMM_CONSUME(r0, ve0, vo0)
            SPMM_CONSUME(r1, ve1, vo1)
        } else {
            SPMM_CONSUME(r0, ve0, vo0)
        }
    }

    // ---- masked parallel tail: remaining 0..15 edges in one burst ----
    int rem = end - e;                   // wave-uniform
    if (rem > 0) {
#pragma unroll
        for (int j = 0; j < 8; j++) {
            int2 c0 = cv[e + 2 * j];
            int2 c1 = cv[e + 2 * j + 1];
            bool val0 = (2 * j)     < rem;   // uniform -> s_cselect
            bool val1 = (2 * j + 1) < rem;
            int ce = __builtin_amdgcn_readfirstlane(c0.x);
            int co = __builtin_amdgcn_readfirstlane(c1.x);
            ce = val0 ? ce : 0;              // clamp BEFORE gather (safe addr)
            co = val1 ? co : 0;
            float ve = val0 ? __int_as_float(__builtin_amdgcn_readfirstlane(c0.y)) : 0.f;
            float vo = val1 ? __int_as_float(__builtin_amdgcn_readfirstlane(c1.y)) : 0.f;
            int col = hi_half ? co : ce;
            uint_t r = xw[(size_t)col * 32 + hl];
            float v = hi_half ? vo : ve;
            ax += v * bflo(r);
            ay += v * bfhi(r);
        }
    }

    // combine halves: both halves end up with the full row sum
    ax += __shfl_xor(ax, 32, 64);
    ay += __shfl_xor(ay, 32, 64);
    return make_float2(ax, ay);
}

__global__ void k_spmm(const int2* __restrict__ ranges, const int2* __restrict__ cv,
                       const ushort_t* __restrict__ xb, ushort_t* __restrict__ out) {
    int row = (blockIdx.x * blockDim.x + threadIdx.x) >> 6;
    int lane = threadIdx.x & 63;
    if (row >= N_NODES) return;
    int hl = lane & 31;
    bool hi_half = lane >= 32;
    row = __builtin_amdgcn_readfirstlane(row);
    int2 rng = ranges[row];
    int beg = __builtin_amdgcn_readfirstlane(rng.x);
    int end = __builtin_amdgcn_readfirstlane(rng.y);
    float2 a = spmm_row(beg, end, hl, hi_half, cv, xb);
    if (!hi_half) {
        uint_t packed = ((uint_t)f32_to_bf16(a.y) << 16) | (uint_t)f32_to_bf16(a.x);
        ((uint_t*)out)[(size_t)row * 32 + hl] = packed;   // dims 2hl, 2hl+1
    }
}

// ---------------------------------------------------------------------------
// k_last: one wave per batch element. Computes layer-3 rows for BOTH the
// user node and item node (two spmm_rows), gathers ego(fp32)+xbA+xbB, and
// emits the dot. Halves are duplicated across lanes 0-31/32-63, so the
// 64-lane reduction double-counts: fold the /2 into the final scale (1/32).
// ---------------------------------------------------------------------------
__global__ void k_last(const int2* __restrict__ ranges, const int2* __restrict__ cv,
                       const int* __restrict__ users, const int* __restrict__ items,
                       const float* __restrict__ ue, const float* __restrict__ ie,
                       const ushort_t* __restrict__ xbA, const ushort_t* __restrict__ xbB,
                       float* __restrict__ out, int batch) {
    int w = (blockIdx.x * blockDim.x + threadIdx.x) >> 6;
    int lane = threadIdx.x & 63;
    if (w >= batch) return;
    int hl = lane & 31;
    bool hi_half = lane >= 32;

    int uu = __builtin_amdgcn_readfirstlane(users[w]);
    int ii = __builtin_amdgcn_readfirstlane(items[w]);
    int row_u = uu;
    int row_i = NUM_USERS + ii;

    // layer-3 contributions (source = xbB)
    int2 ru = ranges[row_u];
    float2 a_u = spmm_row(__builtin_amdgcn_readfirstlane(ru.x),
                          __builtin_amdgcn_readfirstlane(ru.y), hl, hi_half, cv, xbB);
    int2 ri = ranges[row_i];
    float2 a_i = spmm_row(__builtin_amdgcn_readfirstlane(ri.x),
                          __builtin_amdgcn_readfirstlane(ri.y), hl, hi_half, cv, xbB);

    // gathers at dims (2hl, 2hl+1); both halves read the same (broadcast)
    float2 e_u = ((const float2*)(ue + (size_t)uu * EMBED_DIM))[hl];
    float2 e_i = ((const float2*)(ie + (size_t)ii * EMBED_DIM))[hl];
    uint_t Au = ((const uint_t*)xbA)[(size_t)row_u * 32 + hl];
    uint_t Bu = ((const uint_t*)xbB)[(size_t)row_u * 32 + hl];
    uint_t Ai = ((const uint_t*)xbA)[(size_t)row_i * 32 + hl];
    uint_t Bi = ((const uint_t*)xbB)[(size_t)row_i * 32 + hl];

    float ux = e_u.x + bflo(Au) + bflo(Bu) + a_u.x;
    float uy = e_u.y + bfhi(Au) + bfhi(Bu) + a_u.y;
    float ix = e_i.x + bflo(Ai) + bflo(Bi) + a_i.x;
    float iy = e_i.y + bfhi(Ai) + bfhi(Bi) + a_i.y;

    float p = ux * ix + uy * iy;
#pragma unroll
    for (int d = 32; d > 0; d >>= 1) p += __shfl_down(p, d, 64);
    if (lane == 0) out[w] = p * (1.0f / 32.0f);   // 1/16 mean² scale, /2 dup halves
}

// ---------------------------------------------------------------------------

extern "C" void kernel_launch(void* const* d_in, const int* in_sizes, int n_in,
                              void* d_out, int out_size, void* d_ws, size_t ws_size,
                              hipStream_t stream) {
    const int*   users    = (const int*)  d_in[0];
    const int*   items    = (const int*)  d_in[1];
    const int*   adj_rows = (const int*)  d_in[2];
    const int*   adj_cols = (const int*)  d_in[3];
    const float* adj_vals = (const float*)d_in[4];
    const float* user_emb = (const float*)d_in[5];
    const float* item_emb = (const float*)d_in[6];
    float* out = (float*)d_out;

    const int batch = in_sizes[0];
    const int nnz   = in_sizes[2];

    // fixed bucket capacity: mean * 9/8, rounded up to 64 (16-sigma margin)
    int cap = ((nnz / B_BUCKETS) * 9 + 7) / 8;
    cap = (cap + 63) & ~63;
    const size_t padded = (size_t)B_BUCKETS * cap;   // ~5.4M entries

    char* p = (char*)d_ws;
    auto alloc = [&](size_t bytes) -> char* {
        char* r = p;
        p += (bytes + 255) & ~(size_t)255;
        return r;
    };
    const size_t xb_bytes = (size_t)N_NODES * EMBED_DIM * 2;       // 19.2 MB
    int2*     ranges = (int2*) alloc((size_t)N_NODES * 8);
    int*      cursor = (int*)  alloc(NBP * 4);
    int2*     cv     = (int2*) alloc(padded * 8);                  // padded CSR
    // region overlays: staging (build) vs xbA+xbB (layer buffers)
    size_t    region_bytes = padded * 8;
    if (region_bytes < 2 * xb_bytes) region_bytes = 2 * xb_bytes;
    char*     region  = alloc(region_bytes);
    int2*     staging = (int2*)region;
    ushort_t* xbA     = (ushort_t*)region;
    ushort_t* xbB     = (ushort_t*)(region + xb_bytes);
    ushort_t* xb_ego  = (ushort_t*)alloc(xb_bytes);

    const int g_conv  = ((N_NODES * EMBED_DIM / 4) + 511) / 512;   // 4688
    const int g_bin   = (nnz + BIN_CHUNK - 1) / BIN_CHUNK;         // 2344
    const int g_nodes = (N_NODES + 3) / 4;                         // 4 waves/block
    const int g_batch = (batch + 3) / 4;

    // ---- build: convert + fixed-capacity binning (one grid), then scatter ----
    hipMemsetAsync(cursor, 0, NBP * 4, stream);
    k_bin2<<<g_conv + g_bin, 512, 0, stream>>>(user_emb, item_emb, xb_ego,
                                               adj_rows, adj_cols, adj_vals,
                                               cursor, staging, nnz, cap, g_conv);
    k_scatter2b<<<B_BUCKETS, 512, 0, stream>>>(staging, cursor, ranges, cv, cap);

    // ---- layer 1: xbA = A * ego ----
    k_spmm<<<g_nodes, 256, 0, stream>>>(ranges, cv, xb_ego, xbA);

    // ---- layer 2: xbB = A * xbA ----
    k_spmm<<<g_nodes, 256, 0, stream>>>(ranges, cv, xbA, xbB);

    // ---- layer 3 (batch rows only) + gather + dot, fused ----
    k_last<<<g_batch, 256, 0, stream>>>(ranges, cv, users, items,
                                        user_emb, item_emb, xbA, xbB, out, batch);
}